// Round 1
// baseline (1202.633 us; speedup 1.0000x reference)
//
#include <hip/hip_runtime.h>
#include <hip/hip_bf16.h>
#include <stdint.h>

// Fused per-token MHA: 3x (GEMM+LN) -> per-token 16x16 softmax mix -> GEMM.
// bf16 MFMA path (threshold = absmax(ref)*2^-7 allows it; no fp32 MFMA on CDNA4).

typedef __attribute__((ext_vector_type(8))) short short8;
typedef __attribute__((ext_vector_type(8))) unsigned short ushort8;
typedef __attribute__((ext_vector_type(4))) float f32x4;
typedef __attribute__((ext_vector_type(8))) __bf16 bf16x8;

__device__ __forceinline__ unsigned short f2bf(float x) {
    unsigned int u = __builtin_bit_cast(unsigned int, x);
    u += 0x7fffu + ((u >> 16) & 1u);   // round-to-nearest-even
    return (unsigned short)(u >> 16);
}
__device__ __forceinline__ float bf2f(unsigned short h) {
    unsigned int u = ((unsigned int)h) << 16;
    return __builtin_bit_cast(float, u);
}

// ---------------- fp32 -> bf16 cast (memory-bound, vectorized) ----------------
__global__ void cast_kernel(const float* __restrict__ in, unsigned short* __restrict__ out, long n) {
    long i0 = ((long)blockIdx.x * blockDim.x + threadIdx.x) * 8;
    long stride = (long)gridDim.x * blockDim.x * 8;
    for (long i = i0; i < n; i += stride) {
        float4 a = *(const float4*)(in + i);
        float4 b = *(const float4*)(in + i + 4);
        ushort8 r;
        r[0] = f2bf(a.x); r[1] = f2bf(a.y); r[2] = f2bf(a.z); r[3] = f2bf(a.w);
        r[4] = f2bf(b.x); r[5] = f2bf(b.y); r[6] = f2bf(b.z); r[7] = f2bf(b.w);
        *(ushort8*)(out + i) = r;
    }
}

// ---------------- bf16 GEMM: C[M,N] = A[M,K] @ B[N,K]^T + bias ----------------
// m97 structure: 128x128 tile, BK=64, 4 waves (2x2) x 64x64 per wave,
// global_load_lds width 16, single-buffered LDS, 2 barriers per K-step.
template<int OUTF>  // 0: bf16 out, 1: fp32 out
__global__ __launch_bounds__(256, 2) void gemm_bt(
    const unsigned short* __restrict__ A, const unsigned short* __restrict__ B,
    const float* __restrict__ bias, void* __restrict__ C,
    int M, int N, int K)
{
    __shared__ __align__(16) unsigned short lA[128 * 64];
    __shared__ __align__(16) unsigned short lB[128 * 64];
    int tid  = threadIdx.x;
    int lane = tid & 63, wid = tid >> 6;
    int wr = wid >> 1, wc = wid & 1;

    // T1: XCD-aware bijective swizzle (nwg % 8 == 0 for all our launches)
    int nwg = gridDim.x;
    int bid = blockIdx.x;
    int wg  = (bid & 7) * (nwg >> 3) + (bid >> 3);
    int NB  = N >> 7;
    int bm  = wg / NB, bn = wg % NB;

    // staging: thread t loads 16B; row = i*32 + t/8, k-chunk = (t&7)*8
    int srow = tid >> 3;
    int schunk = (tid & 7) * 8;
    size_t aoff0 = (size_t)(bm * 128 + srow) * K + schunk;
    size_t boff0 = (size_t)(bn * 128 + srow) * K + schunk;
    int ldst = tid * 8;  // element offset in LDS per issue (+ i*2048)

    // fragment read bases (linear [row][64] layout)
    int la = (wr * 64 + (lane & 15)) * 64 + (lane >> 4) * 8;
    int lb = (wc * 64 + (lane & 15)) * 64 + (lane >> 4) * 8;

    f32x4 acc[4][4];
    #pragma unroll
    for (int i = 0; i < 4; i++)
        #pragma unroll
        for (int j = 0; j < 4; j++) acc[i][j] = (f32x4){0.f, 0.f, 0.f, 0.f};

    for (int k0 = 0; k0 < K; k0 += 64) {
        #pragma unroll
        for (int i = 0; i < 4; i++) {
            __builtin_amdgcn_global_load_lds(
                (const __attribute__((address_space(1))) void*)(A + aoff0 + (size_t)k0 + (size_t)i * 32 * K),
                (__attribute__((address_space(3))) void*)(lA + ldst + i * 2048), 16, 0, 0);
            __builtin_amdgcn_global_load_lds(
                (const __attribute__((address_space(1))) void*)(B + boff0 + (size_t)k0 + (size_t)i * 32 * K),
                (__attribute__((address_space(3))) void*)(lB + ldst + i * 2048), 16, 0, 0);
        }
        __syncthreads();  // drains vmcnt + lgkmcnt before barrier

        short8 af[4][2], bf[4][2];
        #pragma unroll
        for (int mi = 0; mi < 4; mi++) {
            af[mi][0] = *(const short8*)(lA + la + mi * 1024);
            af[mi][1] = *(const short8*)(lA + la + mi * 1024 + 32);
        }
        #pragma unroll
        for (int ni = 0; ni < 4; ni++) {
            bf[ni][0] = *(const short8*)(lB + lb + ni * 1024);
            bf[ni][1] = *(const short8*)(lB + lb + ni * 1024 + 32);
        }
        #pragma unroll
        for (int mi = 0; mi < 4; mi++)
            #pragma unroll
            for (int ni = 0; ni < 4; ni++) {
                acc[mi][ni] = __builtin_amdgcn_mfma_f32_16x16x32_bf16(
                    __builtin_bit_cast(bf16x8, af[mi][0]),
                    __builtin_bit_cast(bf16x8, bf[ni][0]), acc[mi][ni], 0, 0, 0);
                acc[mi][ni] = __builtin_amdgcn_mfma_f32_16x16x32_bf16(
                    __builtin_bit_cast(bf16x8, af[mi][1]),
                    __builtin_bit_cast(bf16x8, bf[ni][1]), acc[mi][ni], 0, 0, 0);
            }
        __syncthreads();
    }

    // epilogue: C/D layout col=lane&15, row=(lane>>4)*4+j
    int row0 = bm * 128 + wr * 64 + ((lane >> 4) << 2);
    int col0 = bn * 128 + wc * 64 + (lane & 15);
    #pragma unroll
    for (int ni = 0; ni < 4; ni++) {
        float bv = bias[col0 + ni * 16];
        #pragma unroll
        for (int mi = 0; mi < 4; mi++) {
            #pragma unroll
            for (int j = 0; j < 4; j++) {
                float v = acc[mi][ni][j] + bv;
                size_t idx = (size_t)(row0 + mi * 16 + j) * N + (col0 + ni * 16);
                if (OUTF) ((float*)C)[idx] = v;
                else      ((unsigned short*)C)[idx] = f2bf(v);
            }
        }
    }
}

// ---------------- fused LN(q,k,v) + per-token 16x16 attention ----------------
// One wave per token. q,k staged XOR-swizzled in LDS (kills 256B-stride bank
// conflict on MFMA frag reads); v linear (PV reads are conflict-free).
// Scores computed transposed (mfma(K,Q) -> S^T[g][h]) so softmax over g is a
// 4-reg + shfl_xor(16,32) reduction with no cross-lane transpose.
__device__ __forceinline__ void ln_stage(
    const unsigned short* S, int n, const float* __restrict__ g,
    const float* __restrict__ b, unsigned short* lbuf, int lane, bool swz)
{
    const ushort8* src = (const ushort8*)(S + (size_t)n * 2048);
    float v[32];
    float sum = 0.f, sumsq = 0.f;
    #pragma unroll
    for (int i = 0; i < 4; i++) {
        ushort8 raw = src[lane + i * 64];
        #pragma unroll
        for (int j = 0; j < 8; j++) {
            float f = bf2f(raw[j]);
            v[i * 8 + j] = f; sum += f; sumsq += f * f;
        }
    }
    #pragma unroll
    for (int m = 1; m < 64; m <<= 1) {
        sum += __shfl_xor(sum, m);
        sumsq += __shfl_xor(sumsq, m);
    }
    float mu  = sum * (1.f / 2048.f);
    float var = sumsq * (1.f / 2048.f) - mu * mu;
    float rs  = rsqrtf(var + 1e-5f);
    #pragma unroll
    for (int i = 0; i < 4; i++) {
        int e0 = i * 512 + lane * 8;
        float4 ga = *(const float4*)(g + e0), gb4 = *(const float4*)(g + e0 + 4);
        float4 ba = *(const float4*)(b + e0), bb4 = *(const float4*)(b + e0 + 4);
        float gg[8] = {ga.x, ga.y, ga.z, ga.w, gb4.x, gb4.y, gb4.z, gb4.w};
        float bb[8] = {ba.x, ba.y, ba.z, ba.w, bb4.x, bb4.y, bb4.z, bb4.w};
        ushort8 r;
        #pragma unroll
        for (int j = 0; j < 8; j++) r[j] = f2bf((v[i * 8 + j] - mu) * rs * gg[j] + bb[j]);
        int lb0 = e0 * 2;
        int sb  = swz ? (lb0 ^ (((lb0 >> 8) & 7) << 4)) : lb0;
        *(ushort8*)((char*)lbuf + sb) = r;
    }
}

__global__ __launch_bounds__(256) void ln_attn(
    const unsigned short* Sq, const unsigned short* Sk, const unsigned short* Sv,
    const float* __restrict__ qg, const float* __restrict__ qb,
    const float* __restrict__ kg, const float* __restrict__ kb,
    const float* __restrict__ vg, const float* __restrict__ vb,
    unsigned short* X)  // X may alias Sq (row-private in-place)
{
    __shared__ __align__(16) unsigned short sq[4][2048];
    __shared__ __align__(16) unsigned short sk[4][2048];
    __shared__ __align__(16) unsigned short sv[4][2048];
    __shared__ float satt[4][256];
    int tid = threadIdx.x, lane = tid & 63, wid = tid >> 6;
    int n = blockIdx.x * 4 + wid;

    ln_stage(Sq, n, qg, qb, &sq[wid][0], lane, true);
    ln_stage(Sk, n, kg, kb, &sk[wid][0], lane, true);
    ln_stage(Sv, n, vg, vb, &sv[wid][0], lane, false);
    __syncthreads();

    // S^T[g][h] = sum_d k[g][d] q[h][d]
    f32x4 sc = (f32x4){0.f, 0.f, 0.f, 0.f};
    {
        int g = lane & 15;
        int koff = (lane >> 4) * 16;
        int swz = (g & 7) << 4;
        const char* kb_ = (const char*)&sk[wid][0];
        const char* qb_ = (const char*)&sq[wid][0];
        #pragma unroll
        for (int dc = 0; dc < 4; dc++) {
            int off = g * 256 + ((dc * 64 + koff) ^ swz);
            short8 kf = *(const short8*)(kb_ + off);
            short8 qf = *(const short8*)(qb_ + off);
            sc = __builtin_amdgcn_mfma_f32_16x16x32_bf16(
                __builtin_bit_cast(bf16x8, kf), __builtin_bit_cast(bf16x8, qf), sc, 0, 0, 0);
        }
    }
    const float scale = 0.08838834764831845f;  // 1/sqrt(128)
    float s0 = sc[0] * scale, s1 = sc[1] * scale, s2 = sc[2] * scale, s3 = sc[3] * scale;
    float m = fmaxf(fmaxf(s0, s1), fmaxf(s2, s3));
    m = fmaxf(m, __shfl_xor(m, 16));
    m = fmaxf(m, __shfl_xor(m, 32));
    float e0 = __expf(s0 - m), e1 = __expf(s1 - m), e2 = __expf(s2 - m), e3 = __expf(s3 - m);
    float ss = e0 + e1 + e2 + e3;
    ss += __shfl_xor(ss, 16);
    ss += __shfl_xor(ss, 32);
    float inv = 1.f / ss;
    {
        int h = lane & 15, g0 = (lane >> 4) * 4;
        satt[wid][h * 16 + g0 + 0] = e0 * inv;
        satt[wid][h * 16 + g0 + 1] = e1 * inv;
        satt[wid][h * 16 + g0 + 2] = e2 * inv;
        satt[wid][h * 16 + g0 + 3] = e3 * inv;
    }
    __syncthreads();

    // X[h][d] = sum_g att[h][g] * v[g][d]  (VALU; v reads broadcast/conflict-free)
    unsigned short* xrow = X + (size_t)n * 2048;
    #pragma unroll
    for (int i = 0; i < 4; i++) {
        int h = i * 4 + (lane >> 4);
        int d0 = (lane & 15) * 8;
        float acc[8] = {0, 0, 0, 0, 0, 0, 0, 0};
        #pragma unroll
        for (int g = 0; g < 16; g++) {
            float a = satt[wid][h * 16 + g];
            ushort8 vv = *(const ushort8*)&sv[wid][g * 128 + d0];
            #pragma unroll
            for (int j = 0; j < 8; j++) acc[j] += a * bf2f(vv[j]);
        }
        ushort8 r;
        #pragma unroll
        for (int j = 0; j < 8; j++) r[j] = f2bf(acc[j]);
        *(ushort8*)(xrow + i * 512 + lane * 8) = r;  // == row offset h*128+d0
    }
}

// ---------------- launch ----------------
extern "C" void kernel_launch(void* const* d_in, const int* in_sizes, int n_in,
                              void* d_out, int out_size, void* d_ws, size_t ws_size,
                              hipStream_t stream)
{
    (void)in_sizes; (void)n_in; (void)out_size; (void)ws_size;
    const float* query  = (const float*)d_in[0];
    const float* keys   = (const float*)d_in[1];
    const float* values = (const float*)d_in[2];
    const float* Wq = (const float*)d_in[3];
    const float* Wk = (const float*)d_in[4];
    const float* Wv = (const float*)d_in[5];
    const float* Wo = (const float*)d_in[6];
    const float* bq = (const float*)d_in[7];
    const float* bk = (const float*)d_in[8];
    const float* bv = (const float*)d_in[9];
    const float* bo = (const float*)d_in[10];
    const float* q_g = (const float*)d_in[11];
    const float* q_b = (const float*)d_in[12];
    const float* k_g = (const float*)d_in[13];
    const float* k_b = (const float*)d_in[14];
    const float* v_g = (const float*)d_in[15];
    const float* v_b = (const float*)d_in[16];

    const long WN = 2048L * 2048L;
    const long AN = 16384L * 2048L;

    unsigned short* wWq = (unsigned short*)d_ws;
    unsigned short* wWk = wWq + WN;
    unsigned short* wWv = wWk + WN;
    unsigned short* wWo = wWv + WN;
    unsigned short* act = wWo + WN;       // reused for q/k/v activations
    unsigned short* Sq  = act + AN;       // pre-LN q; later overwritten by x
    unsigned short* Sk  = Sq + AN;
    unsigned short* Sv  = Sk + AN;
    // ws usage: 4*8.4MB + 4*67.1MB = 302 MB

    dim3 blk(256);
    cast_kernel<<<512, blk, 0, stream>>>(Wq, wWq, WN);
    cast_kernel<<<512, blk, 0, stream>>>(Wk, wWk, WN);
    cast_kernel<<<512, blk, 0, stream>>>(Wv, wWv, WN);
    cast_kernel<<<512, blk, 0, stream>>>(Wo, wWo, WN);

    dim3 ggrid(2048);  // (16384/128)*(2048/128)
    cast_kernel<<<2048, blk, 0, stream>>>(query, act, AN);
    gemm_bt<0><<<ggrid, blk, 0, stream>>>(act, wWq, bq, Sq, 16384, 2048, 2048);
    cast_kernel<<<2048, blk, 0, stream>>>(keys, act, AN);
    gemm_bt<0><<<ggrid, blk, 0, stream>>>(act, wWk, bk, Sk, 16384, 2048, 2048);
    cast_kernel<<<2048, blk, 0, stream>>>(values, act, AN);
    gemm_bt<0><<<ggrid, blk, 0, stream>>>(act, wWv, bv, Sv, 16384, 2048, 2048);

    ln_attn<<<4096, blk, 0, stream>>>(Sq, Sk, Sv, q_g, q_b, k_g, k_b, v_g, v_b, Sq);

    gemm_bt<1><<<ggrid, blk, 0, stream>>>(Sq, wWo, bo, d_out, 16384, 2048, 2048);
}